// Round 5
// baseline (4956.118 us; speedup 1.0000x reference)
//
#include <hip/hip_runtime.h>

// HMM forward (CgpHmmLayer): B=64, T=4096, S=305.
// prep_A: row-softmax transition kernel -> d_ws as padded 320x320 f32.
// hmm_fwd: one WG per batch element (64 WGs, 512 thr = 8 waves).
//   Wave w owns rows [40w,40w+40); lane l owns cols {l,l+64,...,l+256}.
//   A-slice = 200 NAMED scalar floats per thread. Each value is pinned with
//   asm volatile("" : "+v"(x)) -> value flows through a volatile asm, so the
//   allocator CANNOT rematerialize the global load inside the t-loop (round 4:
//   remat of invariant wsA loads at 128-VGPR occupancy target caused 400KB/block
//   per step of L2 traffic -> L2-BW-bound at 1.16us/step).
//   amdgpu_waves_per_eu(2,2) pins the occupancy target at 2 waves/EU -> 256 VGPR
//   budget, so 200 A + ~30 working fits with no spill.
//   Per step: 40 readlane broadcasts + 200 fmac, partial column sums via
//   ping-pong LDS buffer, ONE barrier/step; each wave gathers exactly its own
//   40 columns (= its rows next step). Normalize every 8 steps; log telescopes;
//   init-softmax normalizer folded into final -log(Z_I).

constexpr int NS  = 305;
constexpr int NSP = 320;
constexpr int NT  = 4096;
constexpr int NW  = 8;
constexpr int RPW = 40;   // rows per wave
constexpr int NORM_MASK = 7;

#define FORTY(X) X(0) X(1) X(2) X(3) X(4) X(5) X(6) X(7) X(8) X(9) \
  X(10) X(11) X(12) X(13) X(14) X(15) X(16) X(17) X(18) X(19) \
  X(20) X(21) X(22) X(23) X(24) X(25) X(26) X(27) X(28) X(29) \
  X(30) X(31) X(32) X(33) X(34) X(35) X(36) X(37) X(38) X(39)

__global__ __launch_bounds__(64)
void prep_A(const float* __restrict__ transk, float* __restrict__ wsA)
{
    const int r = blockIdx.x;      // padded row 0..319
    const int l = threadIdx.x;     // lane 0..63
    if (r < NS) {
        float e[5];
        float part = 0.f;
        #pragma unroll
        for (int k = 0; k < 5; ++k) {
            const int c = l + 64 * k;
            e[k] = (c < NS) ? __expf(transk[r * NS + c]) : 0.f;
            part += e[k];
        }
        #pragma unroll
        for (int off = 32; off; off >>= 1) part += __shfl_xor(part, off, 64);
        const float inv = 1.f / part;
        #pragma unroll
        for (int k = 0; k < 5; ++k)
            wsA[r * NSP + l + 64 * k] = e[k] * inv;
    } else {
        #pragma unroll
        for (int k = 0; k < 5; ++k)
            wsA[r * NSP + l + 64 * k] = 0.f;
    }
}

__global__ __launch_bounds__(512)
__attribute__((amdgpu_waves_per_eu(2, 2)))
void hmm_fwd(const float* __restrict__ inputs,
             const float* __restrict__ initk,
             const float* __restrict__ emisk,
             const float* __restrict__ wsA,
             float* __restrict__ out)
{
    __shared__ float sBm[4 * NSP];
    __shared__ float sI[NSP];
    __shared__ unsigned char sObs[NT];
    __shared__ float sPart[2][NW * NSP];
    __shared__ float sN[16];

    const int tid = threadIdx.x;
    const int w   = tid >> 6;
    const int l   = tid & 63;
    const int b   = blockIdx.x;

    for (int i = tid; i < 4 * NSP; i += 512) sBm[i] = 0.f;
    for (int i = tid; i < NSP;     i += 512) sI[i]  = 0.f;
    __syncthreads();

    // decode one-hot observations (coalesced float4)
    const float4* oh = (const float4*)(inputs + (size_t)b * NT * 4);
    #pragma unroll
    for (int i = 0; i < NT / 512; ++i) {
        int t = tid + i * 512;
        float4 v = oh[t];
        sObs[t] = (unsigned char)(int)(v.y + 2.f * v.z + 3.f * v.w + 0.5f);
    }

    // emission softmax over 4
    if (tid < NS) {
        float4 ek = ((const float4*)emisk)[tid];
        float e0 = __expf(ek.x), e1 = __expf(ek.y), e2 = __expf(ek.z), e3 = __expf(ek.w);
        float inv = 1.f / (e0 + e1 + e2 + e3);
        sBm[0 * NSP + tid] = e0 * inv;
        sBm[1 * NSP + tid] = e1 * inv;
        sBm[2 * NSP + tid] = e2 * inv;
        sBm[3 * NSP + tid] = e3 * inv;
    }

    // init vector: exp only; normalizer folded at the end
    if (tid < NS) sI[tid] = __expf(initk[tid]);
    __syncthreads();

    // log(Z_I)
    float v0 = (tid < NSP) ? sI[tid] : 0.f;
    #pragma unroll
    for (int off = 32; off; off >>= 1) v0 += __shfl_xor(v0, off, 64);
    if (l == 0) sN[w] = v0;
    __syncthreads();
    float z = 0.f;
    #pragma unroll
    for (int i = 0; i < 8; ++i) z += sN[i];
    const float logZI = __logf(z);
    __syncthreads();   // sN safe for reuse

    // ---- A-slice: 200 named scalars, loaded once, PINNED against remat ----
    const float* wa = wsA + (size_t)(w * RPW) * NSP + l;
#define DECLA(J) float a##J##_0, a##J##_1, a##J##_2, a##J##_3, a##J##_4;
    FORTY(DECLA)
#undef DECLA
#define LOADA(J) \
    a##J##_0 = wa[J * NSP];        \
    a##J##_1 = wa[J * NSP + 64];   \
    a##J##_2 = wa[J * NSP + 128];  \
    a##J##_3 = wa[J * NSP + 192];  \
    a##J##_4 = wa[J * NSP + 256];
    FORTY(LOADA)
#undef LOADA
#define PINA(J) asm volatile("" : "+v"(a##J##_0), "+v"(a##J##_1), \
    "+v"(a##J##_2), "+v"(a##J##_3), "+v"(a##J##_4));
    FORTY(PINA)
#undef PINA

    // t = 0
    float va = 0.f;
    {
        int o0 = sObs[0];
        int col = w * RPW + l;
        if (l < RPW) va = sI[col] * sBm[o0 * NSP + col];
    }
    float ll = 0.f;

    // ---- main scan ----
    for (int t = 1; t < NT; ++t) {
        const int o = sObs[t];
        const float ecol = (l < RPW) ? sBm[o * NSP + w * RPW + l] : 0.f;

        float acc0 = 0.f, acc1 = 0.f, acc2 = 0.f, acc3 = 0.f, acc4 = 0.f;
#define FMAA(J) { \
        float sa = __uint_as_float(__builtin_amdgcn_readlane(__float_as_uint(va), J)); \
        acc0 = fmaf(sa, a##J##_0, acc0); \
        acc1 = fmaf(sa, a##J##_1, acc1); \
        acc2 = fmaf(sa, a##J##_2, acc2); \
        acc3 = fmaf(sa, a##J##_3, acc3); \
        acc4 = fmaf(sa, a##J##_4, acc4); }
        FORTY(FMAA)
#undef FMAA

        float* pb = sPart[t & 1];
        pb[w * NSP + l      ] = acc0;
        pb[w * NSP + l +  64] = acc1;
        pb[w * NSP + l + 128] = acc2;
        pb[w * NSP + l + 192] = acc3;
        pb[w * NSP + l + 256] = acc4;
        __syncthreads();

        if (l < RPW) {
            const int col = w * RPW + l;
            float s8 = 0.f;
            #pragma unroll
            for (int ww = 0; ww < NW; ++ww) s8 += pb[ww * NSP + col];
            va = s8 * ecol;
        } else {
            va = 0.f;
        }

        if ((t & NORM_MASK) == NORM_MASK) {
            float v = (l < RPW) ? va : 0.f;
            #pragma unroll
            for (int off = 32; off; off >>= 1) v += __shfl_xor(v, off, 64);
            const int nb = (t >> 3) & 1;
            if (l == 0) sN[nb * 8 + w] = v;
            __syncthreads();
            float tot = 0.f;
            #pragma unroll
            for (int i = 0; i < 8; ++i) tot += sN[nb * 8 + i];
            ll += __logf(tot);
            va *= 1.f / tot;
        }
    }

    if (tid == 0) out[b] = ll - logZI;
}

extern "C" void kernel_launch(void* const* d_in, const int* in_sizes, int n_in,
                              void* d_out, int out_size, void* d_ws, size_t ws_size,
                              hipStream_t stream) {
    const float* inputs = (const float*)d_in[0];
    const float* initk  = (const float*)d_in[1];
    const float* transk = (const float*)d_in[2];
    const float* emisk  = (const float*)d_in[3];
    float* wsA = (float*)d_ws;   // 320*320*4 = 409600 bytes

    hipLaunchKernelGGL(prep_A, dim3(NSP), dim3(64), 0, stream, transk, wsA);
    hipLaunchKernelGGL(hmm_fwd, dim3(64), dim3(512), 0, stream,
                       inputs, initk, emisk, wsA, (float*)d_out);
}